// Round 1
// baseline (236.715 us; speedup 1.0000x reference)
//
#include <hip/hip_runtime.h>

// Pose_Loss: B=65536 rows, D=154 cols, 4 fp32 arrays + 2 int mask arrays.
// out[0] = (dot(use_l, rowsum(recon_l)) + dot(use_r, rowsum(recon_r))) / 154
// out[1] =  dot(use_l, rowsum(KLD_l))   + dot(use_r, rowsum(KLD_r))
// out[2] =  sum(use_l) + sum(use_r)   (integer count, stored as float)

#define BB 65536
#define DD 154

__global__ void zero_out_kernel(float* __restrict__ out) {
    if (threadIdx.x < 3) out[threadIdx.x] = 0.0f;
}

__device__ __forceinline__ void row_weights(int row,
                                            const int* __restrict__ lr,
                                            const int* __restrict__ fp,
                                            float& wl, float& wr) {
    const int l = lr[row];
    const bool valid = (fp[row] != -1);
    wl = (valid && ((l == 0) || (l == 2))) ? 1.0f : 0.0f;
    wr = (valid && ((l == 1) || (l == 2))) ? 1.0f : 0.0f;
}

__global__ __launch_bounds__(256) void pose_loss_kernel(
    const float* __restrict__ recon_l, const float* __restrict__ recon_r,
    const float* __restrict__ kld_l,   const float* __restrict__ kld_r,
    const int* __restrict__ lr,        const int* __restrict__ fp,
    float* __restrict__ out)
{
    const int N4 = (BB * DD) / 4;  // 2,523,136 float4 chunks per array
    const int tid    = blockIdx.x * blockDim.x + threadIdx.x;
    const int stride = gridDim.x * blockDim.x;

    const float4* __restrict__ rl4 = (const float4*)recon_l;
    const float4* __restrict__ rr4 = (const float4*)recon_r;
    const float4* __restrict__ kl4 = (const float4*)kld_l;
    const float4* __restrict__ kr4 = (const float4*)kld_r;

    float acc_recon = 0.0f, acc_kld = 0.0f, acc_cnt = 0.0f;

    for (int i = tid; i < N4; i += stride) {
        const int e  = i * 4;               // max 10,092,540 — fits int32
        const int r0 = e / DD;              // magic-mul const division
        const int r3 = (e + 3) / DD;

        const float4 a = rl4[i];
        const float4 b = rr4[i];
        const float4 c = kl4[i];
        const float4 d = kr4[i];

        if (r0 == r3) {
            // common case: all 4 elements in one row -> one weight pair
            float wl, wr;
            row_weights(r0, lr, fp, wl, wr);
            acc_recon += wl * (a.x + a.y + a.z + a.w)
                       + wr * (b.x + b.y + b.z + b.w);
            acc_kld   += wl * (c.x + c.y + c.z + c.w)
                       + wr * (d.x + d.y + d.z + d.w);
        } else {
            // chunk straddles a row boundary (~1.3% of chunks)
            const float av[4] = {a.x, a.y, a.z, a.w};
            const float bv[4] = {b.x, b.y, b.z, b.w};
            const float cv[4] = {c.x, c.y, c.z, c.w};
            const float dv[4] = {d.x, d.y, d.z, d.w};
#pragma unroll
            for (int j = 0; j < 4; ++j) {
                const int row = (e + j) / DD;
                float wl, wr;
                row_weights(row, lr, fp, wl, wr);
                acc_recon += wl * av[j] + wr * bv[j];
                acc_kld   += wl * cv[j] + wr * dv[j];
            }
        }
    }

    // mask count over the B rows (tiny: 0.5 MB of int loads)
    for (int i = tid; i < BB; i += stride) {
        float wl, wr;
        row_weights(i, lr, fp, wl, wr);
        acc_cnt += wl + wr;
    }

    // wave (64-lane) shuffle reduction
#pragma unroll
    for (int off = 32; off > 0; off >>= 1) {
        acc_recon += __shfl_down(acc_recon, off, 64);
        acc_kld   += __shfl_down(acc_kld,   off, 64);
        acc_cnt   += __shfl_down(acc_cnt,   off, 64);
    }

    __shared__ float s_recon[4], s_kld[4], s_cnt[4];
    const int wave = threadIdx.x >> 6;
    const int lane = threadIdx.x & 63;
    if (lane == 0) {
        s_recon[wave] = acc_recon;
        s_kld[wave]   = acc_kld;
        s_cnt[wave]   = acc_cnt;
    }
    __syncthreads();

    if (threadIdx.x == 0) {
        const float r = s_recon[0] + s_recon[1] + s_recon[2] + s_recon[3];
        const float k = s_kld[0]   + s_kld[1]   + s_kld[2]   + s_kld[3];
        const float c = s_cnt[0]   + s_cnt[1]   + s_cnt[2]   + s_cnt[3];
        atomicAdd(&out[0], r * (1.0f / 154.0f));
        atomicAdd(&out[1], k);
        atomicAdd(&out[2], c);
    }
}

extern "C" void kernel_launch(void* const* d_in, const int* in_sizes, int n_in,
                              void* d_out, int out_size, void* d_ws, size_t ws_size,
                              hipStream_t stream) {
    const float* recon_l = (const float*)d_in[0];
    const float* recon_r = (const float*)d_in[1];
    const float* kld_l   = (const float*)d_in[2];
    const float* kld_r   = (const float*)d_in[3];
    const int*   lr      = (const int*)d_in[4];
    const int*   fp      = (const int*)d_in[5];
    float* out = (float*)d_out;

    zero_out_kernel<<<1, 64, 0, stream>>>(out);
    // 2048 blocks x 256 threads = 524288 threads; ~4.8 float4-quads each.
    pose_loss_kernel<<<2048, 256, 0, stream>>>(recon_l, recon_r, kld_l, kld_r,
                                               lr, fp, out);
}

// Round 2
// 189.371 us; speedup vs baseline: 1.2500x; 1.2500x over previous
//
#include <hip/hip_runtime.h>

// Pose_Loss: B=65536 rows, D=154 cols, 4 fp32 arrays + 2 int mask arrays.
// out[0] = (dot(use_l, rowsum(recon_l)) + dot(use_r, rowsum(recon_r))) / 154
// out[1] =  dot(use_l, rowsum(KLD_l))   + dot(use_r, rowsum(KLD_r))
// out[2] =  sum(use_l) + sum(use_r)   (integer count, stored as float)
//
// Key structural facts:
//  - D = 154 = 2*77  =>  a float2 chunk NEVER straddles a row boundary.
//    A float4 chunk i covers float2 halves 2i and 2i+1 with rows
//    (2i)/77 and (2i+1)/77  -> branch-free per-half weighting.
//  - N4 = B*D/4 = 2,523,136 = 2^15 * 77. Grid 1232*256 = 315,392 = 2^12*77
//    threads => exactly 8 chunks/thread/array, fully unrollable (high MLP).

#define BB 65536
#define DD 154
#define N4 (BB * DD / 4)                       // 2,523,136
#define MAIN_BLOCKS 1232
#define MAIN_THREADS 256
#define TSTRIDE (MAIN_BLOCKS * MAIN_THREADS)   // 315,392
#define ITERS 8                                // N4 / TSTRIDE exactly

__global__ void zero_out_kernel(float* __restrict__ out) {
    if (threadIdx.x < 3) out[threadIdx.x] = 0.0f;
}

__device__ __forceinline__ float2 wpair(int l, int f) {
    const bool valid = (f != -1);
    float2 w;
    w.x = (valid && ((l == 0) || (l == 2))) ? 1.0f : 0.0f;
    w.y = (valid && ((l == 1) || (l == 2))) ? 1.0f : 0.0f;
    return w;
}

__global__ __launch_bounds__(MAIN_THREADS) void pose_loss_kernel(
    const float* __restrict__ recon_l, const float* __restrict__ recon_r,
    const float* __restrict__ kld_l,   const float* __restrict__ kld_r,
    const int* __restrict__ lr,        const int* __restrict__ fp,
    float* __restrict__ out)
{
    const float4* __restrict__ rl4 = (const float4*)recon_l;
    const float4* __restrict__ rr4 = (const float4*)recon_r;
    const float4* __restrict__ kl4 = (const float4*)kld_l;
    const float4* __restrict__ kr4 = (const float4*)kld_r;

    const int t = blockIdx.x * MAIN_THREADS + threadIdx.x;

    float acc_recon = 0.0f, acc_kld = 0.0f, acc_cnt = 0.0f;

#pragma unroll
    for (int it = 0; it < ITERS; ++it) {
        const int i  = t + it * TSTRIDE;       // float4 chunk index
        const int h  = 2 * i;                  // even float2 half index
        const int r0 = h / 77;                 // row of elements 4i, 4i+1
        const int r1 = (h + 1) / 77;           // row of elements 4i+2, 4i+3

        const float2 w0 = wpair(lr[r0], fp[r0]);
        const float2 w1 = wpair(lr[r1], fp[r1]);

        const float4 a = rl4[i];
        const float4 b = rr4[i];
        const float4 c = kl4[i];
        const float4 d = kr4[i];

        acc_recon += w0.x * (a.x + a.y) + w1.x * (a.z + a.w)
                   + w0.y * (b.x + b.y) + w1.y * (b.z + b.w);
        acc_kld   += w0.x * (c.x + c.y) + w1.x * (c.z + c.w)
                   + w0.y * (d.x + d.y) + w1.y * (d.z + d.w);
    }

    // mask count: one row per thread (only first BB threads participate;
    // lr/fp are L2-warm from the main loop's broadcast reads)
    if (t < BB) {
        const float2 w = wpair(lr[t], fp[t]);
        acc_cnt = w.x + w.y;
    }

    // wave (64-lane) shuffle reduction
#pragma unroll
    for (int off = 32; off > 0; off >>= 1) {
        acc_recon += __shfl_down(acc_recon, off, 64);
        acc_kld   += __shfl_down(acc_kld,   off, 64);
        acc_cnt   += __shfl_down(acc_cnt,   off, 64);
    }

    __shared__ float s_recon[4], s_kld[4], s_cnt[4];
    const int wave = threadIdx.x >> 6;
    const int lane = threadIdx.x & 63;
    if (lane == 0) {
        s_recon[wave] = acc_recon;
        s_kld[wave]   = acc_kld;
        s_cnt[wave]   = acc_cnt;
    }
    __syncthreads();

    if (threadIdx.x == 0) {
        const float r = s_recon[0] + s_recon[1] + s_recon[2] + s_recon[3];
        const float k = s_kld[0]   + s_kld[1]   + s_kld[2]   + s_kld[3];
        const float c = s_cnt[0]   + s_cnt[1]   + s_cnt[2]   + s_cnt[3];
        atomicAdd(&out[0], r * (1.0f / 154.0f));
        atomicAdd(&out[1], k);
        atomicAdd(&out[2], c);
    }
}

extern "C" void kernel_launch(void* const* d_in, const int* in_sizes, int n_in,
                              void* d_out, int out_size, void* d_ws, size_t ws_size,
                              hipStream_t stream) {
    const float* recon_l = (const float*)d_in[0];
    const float* recon_r = (const float*)d_in[1];
    const float* kld_l   = (const float*)d_in[2];
    const float* kld_r   = (const float*)d_in[3];
    const int*   lr      = (const int*)d_in[4];
    const int*   fp      = (const int*)d_in[5];
    float* out = (float*)d_out;

    zero_out_kernel<<<1, 64, 0, stream>>>(out);
    pose_loss_kernel<<<MAIN_BLOCKS, MAIN_THREADS, 0, stream>>>(
        recon_l, recon_r, kld_l, kld_r, lr, fp, out);
}

// Round 3
// 178.534 us; speedup vs baseline: 1.3259x; 1.0607x over previous
//
#include <hip/hip_runtime.h>

// Pose_Loss: B=65536 rows, D=154 cols, 4 fp32 arrays + 2 int mask arrays.
// out[0] = (dot(use_l, rowsum(recon_l)) + dot(use_r, rowsum(recon_r))) / 154
// out[1] =  dot(use_l, rowsum(KLD_l))   + dot(use_r, rowsum(KLD_r))
// out[2] =  sum(use_l) + sum(use_r)   (integer count, stored as float)
//
// Structure (R3): max-TLP single-chunk-per-thread.
//  - D = 154 = 2*77 => a float2 half never straddles a row. float4 chunk i
//    covers halves 2i, 2i+1 with rows (2i)/77, (2i+1)/77 (branch-free).
//  - N4 = 2,523,136 = 9856 blocks * 256 threads exactly => ITERS=1,
//    VGPR stays low -> 32 waves/CU resident; 38.5 blocks/CU queued.
//  - Two-stage reduction through d_ws (no same-line atomic storm from
//    9856 blocks); atomic fallback if ws_size too small.

#define BB 65536
#define DD 154
#define N4 (BB * DD / 4)        // 2,523,136
#define BLOCKS 9856             // N4 / 256
#define THREADS 256

__global__ void zero_out_kernel(float* __restrict__ out) {
    if (threadIdx.x < 3) out[threadIdx.x] = 0.0f;
}

__device__ __forceinline__ float2 wpair(int l, int f) {
    const bool valid = (f != -1);
    float2 w;
    w.x = (valid && ((l == 0) || (l == 2))) ? 1.0f : 0.0f;
    w.y = (valid && ((l == 1) || (l == 2))) ? 1.0f : 0.0f;
    return w;
}

// ws layout: ws[0..BLOCKS) = recon partials, [BLOCKS..2B) = kld, [2B..3B) = cnt
__global__ __launch_bounds__(THREADS) void pose_partial_kernel(
    const float* __restrict__ recon_l, const float* __restrict__ recon_r,
    const float* __restrict__ kld_l,   const float* __restrict__ kld_r,
    const int* __restrict__ lr,        const int* __restrict__ fp,
    float* __restrict__ ws,            float* __restrict__ out)
{
    const float4* __restrict__ rl4 = (const float4*)recon_l;
    const float4* __restrict__ rr4 = (const float4*)recon_r;
    const float4* __restrict__ kl4 = (const float4*)kld_l;
    const float4* __restrict__ kr4 = (const float4*)kld_r;

    const int i = blockIdx.x * THREADS + threadIdx.x;   // float4 chunk index
    const int h = 2 * i;
    const int r0 = h / 77;            // row of elements 4i, 4i+1
    const int r1 = (h + 1) / 77;      // row of elements 4i+2, 4i+3

    // issue all big loads up front (independent of the weight gathers)
    const float4 a = rl4[i];
    const float4 b = rr4[i];
    const float4 c = kl4[i];
    const float4 d = kr4[i];

    const float2 w0 = wpair(lr[r0], fp[r0]);
    const float2 w1 = wpair(lr[r1], fp[r1]);

    float acc_recon = w0.x * (a.x + a.y) + w1.x * (a.z + a.w)
                    + w0.y * (b.x + b.y) + w1.y * (b.z + b.w);
    float acc_kld   = w0.x * (c.x + c.y) + w1.x * (c.z + c.w)
                    + w0.y * (d.x + d.y) + w1.y * (d.z + d.w);
    float acc_cnt = 0.0f;
    if (i < BB) {                      // first 256 blocks handle the count
        const float2 w = wpair(lr[i], fp[i]);
        acc_cnt = w.x + w.y;
    }

#pragma unroll
    for (int off = 32; off > 0; off >>= 1) {
        acc_recon += __shfl_down(acc_recon, off, 64);
        acc_kld   += __shfl_down(acc_kld,   off, 64);
        acc_cnt   += __shfl_down(acc_cnt,   off, 64);
    }

    __shared__ float s_recon[4], s_kld[4], s_cnt[4];
    const int wave = threadIdx.x >> 6;
    const int lane = threadIdx.x & 63;
    if (lane == 0) {
        s_recon[wave] = acc_recon;
        s_kld[wave]   = acc_kld;
        s_cnt[wave]   = acc_cnt;
    }
    __syncthreads();

    if (threadIdx.x == 0) {
        const float r = s_recon[0] + s_recon[1] + s_recon[2] + s_recon[3];
        const float k = s_kld[0]   + s_kld[1]   + s_kld[2]   + s_kld[3];
        const float n = s_cnt[0]   + s_cnt[1]   + s_cnt[2]   + s_cnt[3];
        if (ws != nullptr) {
            ws[blockIdx.x]              = r;
            ws[BLOCKS + blockIdx.x]     = k;
            ws[2 * BLOCKS + blockIdx.x] = n;
        } else {
            atomicAdd(&out[0], r * (1.0f / 154.0f));
            atomicAdd(&out[1], k);
            atomicAdd(&out[2], n);
        }
    }
}

__global__ __launch_bounds__(1024) void final_reduce_kernel(
    const float* __restrict__ ws, float* __restrict__ out)
{
    float r = 0.0f, k = 0.0f, n = 0.0f;
    for (int i = threadIdx.x; i < BLOCKS; i += 1024) {
        r += ws[i];
        k += ws[BLOCKS + i];
        n += ws[2 * BLOCKS + i];
    }
#pragma unroll
    for (int off = 32; off > 0; off >>= 1) {
        r += __shfl_down(r, off, 64);
        k += __shfl_down(k, off, 64);
        n += __shfl_down(n, off, 64);
    }
    __shared__ float s_r[16], s_k[16], s_n[16];
    const int wave = threadIdx.x >> 6;
    const int lane = threadIdx.x & 63;
    if (lane == 0) { s_r[wave] = r; s_k[wave] = k; s_n[wave] = n; }
    __syncthreads();
    if (threadIdx.x == 0) {
        float rr = 0.0f, kk = 0.0f, nn = 0.0f;
#pragma unroll
        for (int w = 0; w < 16; ++w) { rr += s_r[w]; kk += s_k[w]; nn += s_n[w]; }
        out[0] = rr * (1.0f / 154.0f);
        out[1] = kk;
        out[2] = nn;
    }
}

extern "C" void kernel_launch(void* const* d_in, const int* in_sizes, int n_in,
                              void* d_out, int out_size, void* d_ws, size_t ws_size,
                              hipStream_t stream) {
    const float* recon_l = (const float*)d_in[0];
    const float* recon_r = (const float*)d_in[1];
    const float* kld_l   = (const float*)d_in[2];
    const float* kld_r   = (const float*)d_in[3];
    const int*   lr      = (const int*)d_in[4];
    const int*   fp      = (const int*)d_in[5];
    float* out = (float*)d_out;

    const bool use_ws = (d_ws != nullptr) &&
                        (ws_size >= (size_t)(3 * BLOCKS) * sizeof(float));
    float* ws = use_ws ? (float*)d_ws : nullptr;

    if (!use_ws) {
        zero_out_kernel<<<1, 64, 0, stream>>>(out);
    }
    pose_partial_kernel<<<BLOCKS, THREADS, 0, stream>>>(
        recon_l, recon_r, kld_l, kld_r, lr, fp, ws, out);
    if (use_ws) {
        final_reduce_kernel<<<1, 1024, 0, stream>>>(ws, out);
    }
}

// Round 4
// 177.903 us; speedup vs baseline: 1.3306x; 1.0035x over previous
//
#include <hip/hip_runtime.h>

// Pose_Loss: B=65536 rows, D=154 cols, 4 fp32 arrays + 2 int mask arrays.
// out[0] = (dot(use_l, rowsum(recon_l)) + dot(use_r, rowsum(recon_r))) / 154
// out[1] =  dot(use_l, rowsum(KLD_l))   + dot(use_r, rowsum(KLD_r))
// out[2] =  sum(use_l) + sum(use_r)   (integer count, stored as float)
//
// R4 structure: ITERS=4 per thread, software-pipelined depth 2.
//  - D = 154 = 2*77 => a float2 half never straddles a row. float4 chunk i
//    covers halves 2i, 2i+1 with rows (2i)/77, (2i+1)/77 (branch-free).
//  - N4 = 2,523,136 = 2464 blocks * 256 threads * 4 iters exactly.
//  - Depth-2 pipeline keeps >=8 float4 loads in flight per thread while
//    consuming, amortizes the shuffle-reduce tail over 4 chunks, and keeps
//    VGPR ~56 (vs 92 in the R2 full-unroll) for 8-waves/SIMD occupancy.
//  - Two-stage reduction through d_ws; atomic fallback if ws too small.

#define BB 65536
#define DD 154
#define N4 (BB * DD / 4)                 // 2,523,136
#define THREADS 256
#define ITERS 4
#define BLOCKS (N4 / (THREADS * ITERS))  // 2464
#define TSTRIDE (BLOCKS * THREADS)       // 630,784

__global__ void zero_out_kernel(float* __restrict__ out) {
    if (threadIdx.x < 3) out[threadIdx.x] = 0.0f;
}

__device__ __forceinline__ float2 wpair(int l, int f) {
    const bool valid = (f != -1);
    float2 w;
    w.x = (valid && ((l == 0) || (l == 2))) ? 1.0f : 0.0f;
    w.y = (valid && ((l == 1) || (l == 2))) ? 1.0f : 0.0f;
    return w;
}

// ws layout: ws[0..BLOCKS) = recon partials, [B..2B) = kld, [2B..3B) = cnt
__global__ __launch_bounds__(THREADS) void pose_partial_kernel(
    const float* __restrict__ recon_l, const float* __restrict__ recon_r,
    const float* __restrict__ kld_l,   const float* __restrict__ kld_r,
    const int* __restrict__ lr,        const int* __restrict__ fp,
    float* __restrict__ ws,            float* __restrict__ out)
{
    const float4* __restrict__ rl4 = (const float4*)recon_l;
    const float4* __restrict__ rr4 = (const float4*)recon_r;
    const float4* __restrict__ kl4 = (const float4*)kld_l;
    const float4* __restrict__ kr4 = (const float4*)kld_r;

    const int t = blockIdx.x * THREADS + threadIdx.x;

    // prime the pipeline: iterations 0 and 1 in flight
    float4 A[2], Bv[2], Cv[2], Dv[2];
    A[0]  = rl4[t];           Bv[0] = rr4[t];
    Cv[0] = kl4[t];           Dv[0] = kr4[t];
    A[1]  = rl4[t + TSTRIDE]; Bv[1] = rr4[t + TSTRIDE];
    Cv[1] = kl4[t + TSTRIDE]; Dv[1] = kr4[t + TSTRIDE];

    float acc_recon = 0.0f, acc_kld = 0.0f, acc_cnt = 0.0f;

#pragma unroll
    for (int k = 0; k < ITERS; ++k) {
        const int buf = k & 1;
        const int idx = t + k * TSTRIDE;
        const int h   = 2 * idx;
        const int r0  = h / 77;           // row of elements 4idx, 4idx+1
        const int r1  = (h + 1) / 77;     // row of elements 4idx+2, 4idx+3

        const float2 w0 = wpair(lr[r0], fp[r0]);
        const float2 w1 = wpair(lr[r1], fp[r1]);

        const float4 a = A[buf], b = Bv[buf], c = Cv[buf], d = Dv[buf];

        if (k + 2 < ITERS) {              // issue iteration k+2's loads
            const int nidx = t + (k + 2) * TSTRIDE;
            A[buf]  = rl4[nidx];  Bv[buf] = rr4[nidx];
            Cv[buf] = kl4[nidx];  Dv[buf] = kr4[nidx];
        }

        acc_recon += w0.x * (a.x + a.y) + w1.x * (a.z + a.w)
                   + w0.y * (b.x + b.y) + w1.y * (b.z + b.w);
        acc_kld   += w0.x * (c.x + c.y) + w1.x * (c.z + c.w)
                   + w0.y * (d.x + d.y) + w1.y * (d.z + d.w);
    }

    // mask count: first BB threads handle one row each (lr/fp are L1/L2-warm)
    if (t < BB) {
        const float2 w = wpair(lr[t], fp[t]);
        acc_cnt = w.x + w.y;
    }

    // wave (64-lane) shuffle reduction
#pragma unroll
    for (int off = 32; off > 0; off >>= 1) {
        acc_recon += __shfl_down(acc_recon, off, 64);
        acc_kld   += __shfl_down(acc_kld,   off, 64);
        acc_cnt   += __shfl_down(acc_cnt,   off, 64);
    }

    __shared__ float s_recon[4], s_kld[4], s_cnt[4];
    const int wave = threadIdx.x >> 6;
    const int lane = threadIdx.x & 63;
    if (lane == 0) {
        s_recon[wave] = acc_recon;
        s_kld[wave]   = acc_kld;
        s_cnt[wave]   = acc_cnt;
    }
    __syncthreads();

    if (threadIdx.x == 0) {
        const float r = s_recon[0] + s_recon[1] + s_recon[2] + s_recon[3];
        const float k = s_kld[0]   + s_kld[1]   + s_kld[2]   + s_kld[3];
        const float n = s_cnt[0]   + s_cnt[1]   + s_cnt[2]   + s_cnt[3];
        if (ws != nullptr) {
            ws[blockIdx.x]              = r;
            ws[BLOCKS + blockIdx.x]     = k;
            ws[2 * BLOCKS + blockIdx.x] = n;
        } else {
            atomicAdd(&out[0], r * (1.0f / 154.0f));
            atomicAdd(&out[1], k);
            atomicAdd(&out[2], n);
        }
    }
}

__global__ __launch_bounds__(1024) void final_reduce_kernel(
    const float* __restrict__ ws, float* __restrict__ out)
{
    float r = 0.0f, k = 0.0f, n = 0.0f;
    for (int i = threadIdx.x; i < BLOCKS; i += 1024) {
        r += ws[i];
        k += ws[BLOCKS + i];
        n += ws[2 * BLOCKS + i];
    }
#pragma unroll
    for (int off = 32; off > 0; off >>= 1) {
        r += __shfl_down(r, off, 64);
        k += __shfl_down(k, off, 64);
        n += __shfl_down(n, off, 64);
    }
    __shared__ float s_r[16], s_k[16], s_n[16];
    const int wave = threadIdx.x >> 6;
    const int lane = threadIdx.x & 63;
    if (lane == 0) { s_r[wave] = r; s_k[wave] = k; s_n[wave] = n; }
    __syncthreads();
    if (threadIdx.x == 0) {
        float rr = 0.0f, kk = 0.0f, nn = 0.0f;
#pragma unroll
        for (int w = 0; w < 16; ++w) { rr += s_r[w]; kk += s_k[w]; nn += s_n[w]; }
        out[0] = rr * (1.0f / 154.0f);
        out[1] = kk;
        out[2] = nn;
    }
}

extern "C" void kernel_launch(void* const* d_in, const int* in_sizes, int n_in,
                              void* d_out, int out_size, void* d_ws, size_t ws_size,
                              hipStream_t stream) {
    const float* recon_l = (const float*)d_in[0];
    const float* recon_r = (const float*)d_in[1];
    const float* kld_l   = (const float*)d_in[2];
    const float* kld_r   = (const float*)d_in[3];
    const int*   lr      = (const int*)d_in[4];
    const int*   fp      = (const int*)d_in[5];
    float* out = (float*)d_out;

    const bool use_ws = (d_ws != nullptr) &&
                        (ws_size >= (size_t)(3 * BLOCKS) * sizeof(float));
    float* ws = use_ws ? (float*)d_ws : nullptr;

    if (!use_ws) {
        zero_out_kernel<<<1, 64, 0, stream>>>(out);
    }
    pose_partial_kernel<<<BLOCKS, THREADS, 0, stream>>>(
        recon_l, recon_r, kld_l, kld_r, lr, fp, ws, out);
    if (use_ws) {
        final_reduce_kernel<<<1, 1024, 0, stream>>>(ws, out);
    }
}

// Round 6
// 165.118 us; speedup vs baseline: 1.4336x; 1.0774x over previous
//
#include <hip/hip_runtime.h>

// Pose_Loss: B=65536 rows, D=154 cols, 4 fp32 arrays + 2 int mask arrays.
// out[0] = (dot(use_l, rowsum(recon_l)) + dot(use_r, rowsum(recon_r))) / 154
// out[1] =  dot(use_l, rowsum(KLD_l))   + dot(use_r, rowsum(KLD_r))
// out[2] =  sum(use_l) + sum(use_r)   (integer count, stored as float)
//
// R6 = R5 with the nontemporal builtin applied to a native clang vector
// type (__builtin_nontemporal_load rejects HIP_vector_type wrappers).
// Theory under test (from R4 post-mortem): delivered BW is pinned at
// ~2.9 TB/s regardless of occupancy/ILP because the harness's per-replay
// 162 MB input restore leaves dirty L3 lines; our fetch write-allocates
// and evicts them -> hidden in-window HBM writeback. `nt` loads skip L3
// allocation -> no dirty evictions in the timed window.
//  - D = 154 = 2*77 => a float2 half never straddles a row. float4 chunk i
//    covers halves 2i, 2i+1 with rows (2i)/77, (2i+1)/77 (branch-free).
//  - N4 = 2,523,136 = 9856 blocks * 256 threads exactly.
//  - Two-stage reduction through d_ws; atomic fallback if ws too small.

#define BB 65536
#define DD 154
#define N4 (BB * DD / 4)        // 2,523,136
#define BLOCKS 9856             // N4 / 256
#define THREADS 256

typedef float nt_float4 __attribute__((ext_vector_type(4)));

__global__ void zero_out_kernel(float* __restrict__ out) {
    if (threadIdx.x < 3) out[threadIdx.x] = 0.0f;
}

__device__ __forceinline__ float2 wpair(int l, int f) {
    const bool valid = (f != -1);
    float2 w;
    w.x = (valid && ((l == 0) || (l == 2))) ? 1.0f : 0.0f;
    w.y = (valid && ((l == 1) || (l == 2))) ? 1.0f : 0.0f;
    return w;
}

// ws layout: ws[0..BLOCKS) = recon partials, [B..2B) = kld, [2B..3B) = cnt
__global__ __launch_bounds__(THREADS) void pose_partial_kernel(
    const float* __restrict__ recon_l, const float* __restrict__ recon_r,
    const float* __restrict__ kld_l,   const float* __restrict__ kld_r,
    const int* __restrict__ lr,        const int* __restrict__ fp,
    float* __restrict__ ws,            float* __restrict__ out)
{
    const nt_float4* __restrict__ rl4 = (const nt_float4*)recon_l;
    const nt_float4* __restrict__ rr4 = (const nt_float4*)recon_r;
    const nt_float4* __restrict__ kl4 = (const nt_float4*)kld_l;
    const nt_float4* __restrict__ kr4 = (const nt_float4*)kld_r;

    const int i = blockIdx.x * THREADS + threadIdx.x;   // float4 chunk index
    const int h = 2 * i;
    const int r0 = h / 77;            // row of elements 4i, 4i+1
    const int r1 = (h + 1) / 77;      // row of elements 4i+2, 4i+3

    // non-temporal streaming loads: read once, do not allocate in cache
    const nt_float4 a = __builtin_nontemporal_load(&rl4[i]);
    const nt_float4 b = __builtin_nontemporal_load(&rr4[i]);
    const nt_float4 c = __builtin_nontemporal_load(&kl4[i]);
    const nt_float4 d = __builtin_nontemporal_load(&kr4[i]);

    // weight lookups stay cached (tiny, heavily reused across lanes)
    const float2 w0 = wpair(lr[r0], fp[r0]);
    const float2 w1 = wpair(lr[r1], fp[r1]);

    float acc_recon = w0.x * (a.x + a.y) + w1.x * (a.z + a.w)
                    + w0.y * (b.x + b.y) + w1.y * (b.z + b.w);
    float acc_kld   = w0.x * (c.x + c.y) + w1.x * (c.z + c.w)
                    + w0.y * (d.x + d.y) + w1.y * (d.z + d.w);
    float acc_cnt = 0.0f;
    if (i < BB) {                      // first 256 blocks: coalesced count
        const float2 w = wpair(lr[i], fp[i]);
        acc_cnt = w.x + w.y;
    }

#pragma unroll
    for (int off = 32; off > 0; off >>= 1) {
        acc_recon += __shfl_down(acc_recon, off, 64);
        acc_kld   += __shfl_down(acc_kld,   off, 64);
        acc_cnt   += __shfl_down(acc_cnt,   off, 64);
    }

    __shared__ float s_recon[4], s_kld[4], s_cnt[4];
    const int wave = threadIdx.x >> 6;
    const int lane = threadIdx.x & 63;
    if (lane == 0) {
        s_recon[wave] = acc_recon;
        s_kld[wave]   = acc_kld;
        s_cnt[wave]   = acc_cnt;
    }
    __syncthreads();

    if (threadIdx.x == 0) {
        const float r = s_recon[0] + s_recon[1] + s_recon[2] + s_recon[3];
        const float k = s_kld[0]   + s_kld[1]   + s_kld[2]   + s_kld[3];
        const float n = s_cnt[0]   + s_cnt[1]   + s_cnt[2]   + s_cnt[3];
        if (ws != nullptr) {
            ws[blockIdx.x]              = r;
            ws[BLOCKS + blockIdx.x]     = k;
            ws[2 * BLOCKS + blockIdx.x] = n;
        } else {
            atomicAdd(&out[0], r * (1.0f / 154.0f));
            atomicAdd(&out[1], k);
            atomicAdd(&out[2], n);
        }
    }
}

__global__ __launch_bounds__(1024) void final_reduce_kernel(
    const float* __restrict__ ws, float* __restrict__ out)
{
    float r = 0.0f, k = 0.0f, n = 0.0f;
    for (int i = threadIdx.x; i < BLOCKS; i += 1024) {
        r += ws[i];
        k += ws[BLOCKS + i];
        n += ws[2 * BLOCKS + i];
    }
#pragma unroll
    for (int off = 32; off > 0; off >>= 1) {
        r += __shfl_down(r, off, 64);
        k += __shfl_down(k, off, 64);
        n += __shfl_down(n, off, 64);
    }
    __shared__ float s_r[16], s_k[16], s_n[16];
    const int wave = threadIdx.x >> 6;
    const int lane = threadIdx.x & 63;
    if (lane == 0) { s_r[wave] = r; s_k[wave] = k; s_n[wave] = n; }
    __syncthreads();
    if (threadIdx.x == 0) {
        float rr = 0.0f, kk = 0.0f, nn = 0.0f;
#pragma unroll
        for (int w = 0; w < 16; ++w) { rr += s_r[w]; kk += s_k[w]; nn += s_n[w]; }
        out[0] = rr * (1.0f / 154.0f);
        out[1] = kk;
        out[2] = nn;
    }
}

extern "C" void kernel_launch(void* const* d_in, const int* in_sizes, int n_in,
                              void* d_out, int out_size, void* d_ws, size_t ws_size,
                              hipStream_t stream) {
    const float* recon_l = (const float*)d_in[0];
    const float* recon_r = (const float*)d_in[1];
    const float* kld_l   = (const float*)d_in[2];
    const float* kld_r   = (const float*)d_in[3];
    const int*   lr      = (const int*)d_in[4];
    const int*   fp      = (const int*)d_in[5];
    float* out = (float*)d_out;

    const bool use_ws = (d_ws != nullptr) &&
                        (ws_size >= (size_t)(3 * BLOCKS) * sizeof(float));
    float* ws = use_ws ? (float*)d_ws : nullptr;

    if (!use_ws) {
        zero_out_kernel<<<1, 64, 0, stream>>>(out);
    }
    pose_partial_kernel<<<BLOCKS, THREADS, 0, stream>>>(
        recon_l, recon_r, kld_l, kld_r, lr, fp, ws, out);
    if (use_ws) {
        final_reduce_kernel<<<1, 1024, 0, stream>>>(ws, out);
    }
}